// Round 12
// baseline (104.356 us; speedup 1.0000x reference)
//
#include <hip/hip_runtime.h>

// ---------------------------------------------------------------------------
// AttentionBlock: GN(8 groups) -> QKV(768x256) -> 4-head attn (HW=4096, d=64)
//                 -> proj(256x256)+bias -> +xn residual.   B=2, C=256.
// R12: attn with 3-deep K/V prefetch rotation (A,B,C buffer sets, unroll-3):
// doubles the load->use distance (~2 COMPUTE blocks) to cover loaded-L2
// latency that the 1-deep ping-pong left exposed. Everything else = R11.
// ---------------------------------------------------------------------------

typedef short s16x8 __attribute__((ext_vector_type(8)));
typedef float f32x4 __attribute__((ext_vector_type(4)));

#define MFMA16(a, b, c) __builtin_amdgcn_mfma_f32_16x16x32_bf16(a, b, c, 0, 0, 0)

__device__ __forceinline__ short bf16s(float f) {
  union { float f; unsigned u; } v; v.f = f;
  unsigned r = v.u + 0x7fffu + ((v.u >> 16) & 1u);
  return (short)(r >> 16);
}

__device__ __forceinline__ unsigned cvtpk(float lo, float hi) {
  unsigned r;
  asm("v_cvt_pk_bf16_f32 %0, %1, %2" : "=v"(r) : "v"(lo), "v"(hi));
  return r;
}

// 2^x via single v_exp_f32 (hazard-safe builtin). |x| < ~30 in this kernel.
__device__ __forceinline__ float exp_raw(float x) {
  return __builtin_amdgcn_exp2f(x);
}

__device__ __forceinline__ void gload16(const void* g, void* l) {
  __builtin_amdgcn_global_load_lds(
      (const __attribute__((address_space(1))) unsigned*)g,
      (__attribute__((address_space(3))) unsigned*)l, 16, 0, 0);
}

// ---------------- K1: GN partial sums (blk<256) + weight->bf16 (blk>=256) ---
__global__ __launch_bounds__(256) void pre_gn(const float* __restrict__ x,
                                              const float* __restrict__ wq,
                                              const float* __restrict__ wp,
                                              short* __restrict__ wqb,
                                              short* __restrict__ wpb,
                                              float* __restrict__ part) {
  int blk = blockIdx.x;
  int t = threadIdx.x;
  if (blk >= 256) {  // ---- weights -> bf16 ----
    int i = (blk - 256) * 256 + t;
    if (i < 768 * 256) {
      wqb[i] = bf16s(wq[i]);
    } else {
      int j = i - 768 * 256;
      if (j < 256 * 256) wpb[j] = bf16s(wp[j]);
    }
    return;
  }
  // ---- GN partial sums (16 groups x 16 parts) ----
  int gi = blk >> 4, sub = blk & 15;
  const float* base = x + (long)gi * 131072 + sub * 8192;
  float s = 0.f, ss = 0.f;
#pragma unroll
  for (int k = 0; k < 8; k++) {
    float4 v = *(const float4*)(base + t * 4 + k * 1024);
    s += v.x + v.y + v.z + v.w;
    ss += v.x * v.x + v.y * v.y + v.z * v.z + v.w * v.w;
  }
#pragma unroll
  for (int m = 1; m < 64; m <<= 1) { s += __shfl_xor(s, m); ss += __shfl_xor(ss, m); }
  __shared__ float red[8];
  int wv = t >> 6;
  if ((t & 63) == 0) { red[wv * 2] = s; red[wv * 2 + 1] = ss; }
  __syncthreads();
  if (t == 0) {
    float S = 0.f, SS = 0.f;
    for (int w = 0; w < 4; w++) { S += red[w * 2]; SS += red[w * 2 + 1]; }
    part[blk * 2] = S; part[blk * 2 + 1] = SS;
  }
}

// stats-from-partials prologue (16 groups; g = b*8 + c/32)
__device__ __forceinline__ void stats_prologue(const float* __restrict__ part,
                                               float* sstats, int t) {
  if (t < 16) {
    float S = 0.f, SS = 0.f;
#pragma unroll
    for (int i = 0; i < 16; i++) {
      S += part[(t * 16 + i) * 2];
      SS += part[(t * 16 + i) * 2 + 1];
    }
    float mean = S * (1.0f / 131072.0f);
    float var = SS * (1.0f / 131072.0f) - mean * mean;
    sstats[t * 2] = mean;
    sstats[t * 2 + 1] = rsqrtf(var + 1e-5f);
  }
}

// ---------------- K2: normalize + transpose -> xnT bf16 (p,c) --------------
__global__ __launch_bounds__(256) void gn_norm_t(const float* __restrict__ x,
                                                 const float* __restrict__ gamma,
                                                 const float* __restrict__ beta,
                                                 const float* __restrict__ part,
                                                 short* __restrict__ xnT) {
  __shared__ __align__(16) short T[64 * 88];
  __shared__ float sstats[32];
  int bx = blockIdx.x;
  int pt = bx & 63, ct = (bx >> 6) & 3, b = bx >> 8;
  int t = threadIdx.x;
  stats_prologue(part, sstats, t);
  __syncthreads();
#pragma unroll
  for (int it = 0; it < 4; it++) {
    int chunk = t + it * 256;
    int c_loc = chunk >> 4, pch = chunk & 15;
    int c = ct * 64 + c_loc;
    int g = b * 8 + (c >> 5);
    float mean = sstats[g * 2], rstd = sstats[g * 2 + 1];
    float ga = gamma[c] * rstd;
    float be = beta[c] - mean * ga;
    long idx = ((long)(b * 256 + c)) * 4096 + pt * 64 + pch * 4;
    float4 v = *(const float4*)(x + idx);
    float4 n = {v.x * ga + be, v.y * ga + be, v.z * ga + be, v.w * ga + be};
    int p0 = pch * 4;
    T[(p0 + 0) * 88 + c_loc] = bf16s(n.x);
    T[(p0 + 1) * 88 + c_loc] = bf16s(n.y);
    T[(p0 + 2) * 88 + c_loc] = bf16s(n.z);
    T[(p0 + 3) * 88 + c_loc] = bf16s(n.w);
  }
  __syncthreads();
#pragma unroll
  for (int it = 0; it < 2; it++) {
    int chunk = t + it * 256;
    int p_loc = chunk >> 3, cch = chunk & 7;
    s16x8 v = *(const s16x8*)&T[p_loc * 88 + cch * 8];
    *(s16x8*)&xnT[((long)(b * 4096 + pt * 64 + p_loc)) * 256 + ct * 64 + cch * 8] = v;
  }
}

// ---------------- K3: QKV TN-GEMM, M-tile 64 --------------------------------
__global__ __launch_bounds__(256) void qkv_gemm(const short* __restrict__ xnT,
                                                const short* __restrict__ wqb,
                                                short* __restrict__ qT,
                                                short* __restrict__ kP,
                                                short* __restrict__ vP) {
  __shared__ __align__(16) short smem[8320];  // As(2048)+Bs(4096) | Ts 64x130
  short* As = smem;
  short* Bs = smem + 2048;
  int m0 = blockIdx.x * 64, n0 = blockIdx.y * 128, b = blockIdx.z;
  const short* A = xnT + (long)b * 4096 * 256;
  int t = threadIdx.x, wv = t >> 6, lane = t & 63, lg = lane >> 4, lq = lane & 15;
  int wr = wv >> 1, wc = wv & 1;
  f32x4 acc[2][4] = {};
  for (int kt = 0; kt < 8; kt++) {
    int k0 = kt * 32;
    {
      int row = t >> 2, kch = t & 3;
      int kk = kch ^ ((row >> 1) & 3);
      gload16(A + (m0 + row) * 256 + k0 + kk * 8, &As[wv * 512]);
    }
#pragma unroll
    for (int it = 0; it < 2; it++) {
      int chunk = t + it * 256;
      int row = chunk >> 2, kch = chunk & 3;
      int kk = kch ^ ((row >> 1) & 3);
      gload16(wqb + (n0 + row) * 256 + k0 + kk * 8, &Bs[it * 2048 + wv * 512]);
    }
    __syncthreads();
    s16x8 af[2], bfr[4];
#pragma unroll
    for (int mi = 0; mi < 2; mi++) {
      int row = wr * 32 + mi * 16 + lq;
      af[mi] = *(const s16x8*)&As[row * 32 + ((lg ^ ((row >> 1) & 3)) << 3)];
    }
#pragma unroll
    for (int ni = 0; ni < 4; ni++) {
      int row = wc * 64 + ni * 16 + lq;
      bfr[ni] = *(const s16x8*)&Bs[row * 32 + ((lg ^ ((row >> 1) & 3)) << 3)];
    }
#pragma unroll
    for (int mi = 0; mi < 2; mi++)
#pragma unroll
      for (int ni = 0; ni < 4; ni++)
        acc[mi][ni] = MFMA16(af[mi], bfr[ni], acc[mi][ni]);
    __syncthreads();
  }
  if (blockIdx.y < 2) {  // ---- Q ----
    short* Out = qT + (long)b * 4096 * 256;
#pragma unroll
    for (int mi = 0; mi < 2; mi++)
#pragma unroll
      for (int ni = 0; ni < 4; ni++) {
        int p = m0 + wr * 32 + mi * 16 + (lg << 2);
        int o = n0 + wc * 64 + ni * 16 + lq;
#pragma unroll
        for (int r = 0; r < 4; r++)
          Out[(long)(p + r) * 256 + o] = bf16s(acc[mi][ni][r] * 0.180336880f);
      }
  } else if (blockIdx.y < 4) {  // ---- K: LDS transpose -> coalesced kP ----
    short(*Ts)[130] = (short(*)[130])smem;
#pragma unroll
    for (int mi = 0; mi < 2; mi++)
#pragma unroll
      for (int ni = 0; ni < 4; ni++) {
        int pr = wr * 32 + mi * 16 + (lg << 2);
        int oc = wc * 64 + ni * 16 + lq;
#pragma unroll
        for (int r = 0; r < 4; r++) Ts[pr + r][oc] = bf16s(acc[mi][ni][r]);
      }
    __syncthreads();
    int reg = t >> 6;
    int tl = reg >> 1, hl = reg & 1;
    int l2 = t & 63, lq2 = l2 & 15, lg2 = l2 >> 4;
    int hb = (n0 - 256) >> 6;
    long kb2 = ((long)(b * 4 + hb + hl) * 128 + (m0 >> 5) + tl) * 2048;
#pragma unroll
    for (int f = 0; f < 4; f++) {
      int row = 32 * tl + (lq2 & 3) + 8 * (lq2 >> 2) + 4 * (f >> 1);  // pi(lq2)
      int col = hl * 64 + 32 * (f & 1) + 8 * lg2;
      s16x8 v = *(const s16x8*)&Ts[row][col];
      *(s16x8*)&kP[kb2 + f * 512 + l2 * 8] = v;
    }
  } else {  // ---- V -> vP ----
#pragma unroll
    for (int mi = 0; mi < 2; mi++)
#pragma unroll
      for (int ni = 0; ni < 4; ni++) {
        int p = m0 + wr * 32 + mi * 16 + (lg << 2);
        int c = (n0 - 512) + wc * 64 + ni * 16 + lq;
        int h = c >> 6, ch = c & 63;
        int f = ch >> 4, lqp = ch & 15;
        int tile = p >> 5, lgp = (p & 31) >> 3, e0 = p & 7;
        unsigned u0 = cvtpk(acc[mi][ni][0], acc[mi][ni][1]);
        unsigned u1 = cvtpk(acc[mi][ni][2], acc[mi][ni][3]);
        *(unsigned long long*)&vP[((long)(b * 4 + h) * 128 + tile) * 2048 +
                                  f * 512 + (lgp * 16 + lqp) * 8 + e0] =
            ((unsigned long long)u1 << 32) | u0;
      }
  }
}

// ---------------- K4: flash attention, 3-deep prefetch ----------------------
#define LOADKV(KF, VF, JT)                                                  \
  do {                                                                      \
    long tb_ = ((long)((JT) * 4 + wv)) * 2048 + l * 8;                      \
    KF##0 = *(const s16x8*)(kp + tb_);                                      \
    KF##1 = *(const s16x8*)(kp + tb_ + 512);                                \
    KF##2 = *(const s16x8*)(kp + tb_ + 1024);                               \
    KF##3 = *(const s16x8*)(kp + tb_ + 1536);                               \
    VF##0 = *(const s16x8*)(vp + tb_);                                      \
    VF##1 = *(const s16x8*)(vp + tb_ + 512);                                \
    VF##2 = *(const s16x8*)(vp + tb_ + 1024);                               \
    VF##3 = *(const s16x8*)(vp + tb_ + 1536);                               \
  } while (0)

#define COMPUTE(KF, VF)                                                     \
  do {                                                                      \
    _Pragma("unroll") for (int ig = 0; ig < 4; ig++) {                      \
      f32x4 z0 = {0.f, 0.f, 0.f, 0.f}, z1 = {0.f, 0.f, 0.f, 0.f};           \
      z0 = MFMA16(KF##0, qf[ig][0], z0);                                    \
      z0 = MFMA16(KF##1, qf[ig][1], z0);                                    \
      z1 = MFMA16(KF##2, qf[ig][0], z1);                                    \
      z1 = MFMA16(KF##3, qf[ig][1], z1);                                    \
      f32x4 p0, p1;                                                         \
      _Pragma("unroll") for (int r = 0; r < 4; r++) {                       \
        p0[r] = exp_raw(z0[r]);                                             \
        p1[r] = exp_raw(z1[r]);                                             \
      }                                                                     \
      f32x4 ps = p0 + p1;                                                   \
      lsc[ig] += (ps[0] + ps[1]) + (ps[2] + ps[3]);                         \
      union { unsigned u[4]; s16x8 v; } pb;                                 \
      pb.u[0] = cvtpk(p0[0], p0[1]);                                        \
      pb.u[1] = cvtpk(p0[2], p0[3]);                                        \
      pb.u[2] = cvtpk(p1[0], p1[1]);                                        \
      pb.u[3] = cvtpk(p1[2], p1[3]);                                        \
      oacc[ig][0] = MFMA16(VF##0, pb.v, oacc[ig][0]);                       \
      oacc[ig][1] = MFMA16(VF##1, pb.v, oacc[ig][1]);                       \
      oacc[ig][2] = MFMA16(VF##2, pb.v, oacc[ig][2]);                       \
      oacc[ig][3] = MFMA16(VF##3, pb.v, oacc[ig][3]);                       \
    }                                                                       \
  } while (0)

__global__ __launch_bounds__(256, 2) void attn(const short* __restrict__ qT_,
                                               const short* __restrict__ kP,
                                               const short* __restrict__ vP,
                                               short* __restrict__ ao_) {
  __shared__ __align__(16) f32x4 cb[2 * 1088];  // 2 regions x 17 items x 64 lanes
  int bid = blockIdx.x;
  int bh = bid & 7, itile = bid >> 3;  // bh -> XCD (round-robin)
  int b = bh >> 2, h = bh & 3;
  int i0 = itile * 64;
  const short* kp = kP + (long)bh * 128 * 2048;
  const short* vp = vP + (long)bh * 128 * 2048;
  short* ao = ao_ + (long)b * 4096 * 256;
  int t = threadIdx.x, wv = t >> 6, l = t & 63, lq = l & 15, lg = l >> 4;

  // Q fragments, resident for the whole kernel
  s16x8 qf[4][2];
  const short* qbase = qT_ + (long)b * 4096 * 256 + h * 64;
#pragma unroll
  for (int ig = 0; ig < 4; ig++) {
    const short* qr = qbase + (long)(i0 + ig * 16 + lq) * 256;
    qf[ig][0] = *(const s16x8*)(qr + 8 * lg);
    qf[ig][1] = *(const s16x8*)(qr + 32 + 8 * lg);
  }

  f32x4 oacc[4][4] = {};
  float lsc[4] = {0.f, 0.f, 0.f, 0.f};

  s16x8 ka0, ka1, ka2, ka3, va0, va1, va2, va3;
  s16x8 kb0, kb1, kb2, kb3, vb0, vb1, vb2, vb3;
  s16x8 kc0, kc1, kc2, kc3, vc0, vc1, vc2, vc3;

  LOADKV(ka, va, 0);
  LOADKV(kb, vb, 1);
  for (int jt = 0; jt < 30; jt += 3) {
    LOADKV(kc, vc, jt + 2);
    COMPUTE(ka, va);
    LOADKV(ka, va, jt + 3);
    COMPUTE(kb, vb);
    LOADKV(kb, vb, jt + 4);
    COMPUTE(kc, vc);
  }
  COMPUTE(ka, va);  // jt = 30
  COMPUTE(kb, vb);  // jt = 31

  // ---- l: cross-lg reduce (i = lq lane-local) ----
  f32x4 lv4;
#pragma unroll
  for (int ig = 0; ig < 4; ig++) {
    float s = lsc[ig];
    s += __shfl_xor(s, 16);
    s += __shfl_xor(s, 32);
    lv4[ig] = s;
  }

  // ---- 2-round cross-wave combine tree ----
#define CB_W(REG)                                                           \
  do {                                                                      \
    f32x4* d_ = cb + (REG) * 1088;                                          \
    _Pragma("unroll") for (int ig = 0; ig < 4; ig++)                        \
    _Pragma("unroll") for (int nc = 0; nc < 4; nc++)                        \
        d_[(ig * 4 + nc) * 64 + l] = oacc[ig][nc];                          \
    d_[16 * 64 + l] = lv4;                                                  \
  } while (0)
#define CB_A(REG)                                                           \
  do {                                                                      \
    f32x4* s_ = cb + (REG) * 1088;                                          \
    _Pragma("unroll") for (int ig = 0; ig < 4; ig++)                        \
    _Pragma("unroll") for (int nc = 0; nc < 4; nc++)                        \
        oacc[ig][nc] += s_[(ig * 4 + nc) * 64 + l];                         \
    lv4 += s_[16 * 64 + l];                                                 \
  } while (0)

  if (wv >= 2) CB_W(wv - 2);
  __syncthreads();
  if (wv < 2) CB_A(wv);
  __syncthreads();
  if (wv == 1) CB_W(0);
  __syncthreads();
  if (wv == 0) {
    CB_A(0);
#pragma unroll
    for (int ig = 0; ig < 4; ig++) {
      float inv = 1.0f / lv4[ig];
      long irow = i0 + ig * 16 + lq;
#pragma unroll
      for (int nc = 0; nc < 4; nc++) {
        f32x4 o = oacc[ig][nc];
        unsigned u0 = cvtpk(o[0] * inv, o[1] * inv);
        unsigned u1 = cvtpk(o[2] * inv, o[3] * inv);
        *(unsigned long long*)&ao[irow * 256 + h * 64 + nc * 16 + 4 * lg] =
            ((unsigned long long)u1 << 32) | u0;
      }
    }
  }
}

// ---------------- K5: proj TN-GEMM (M-tile 64) + bias + GN residual --------
__global__ __launch_bounds__(256) void proj_gemm(const short* __restrict__ ao,
                                                 const short* __restrict__ wpb,
                                                 const float* __restrict__ bproj,
                                                 const float* __restrict__ x,
                                                 const float* __restrict__ gamma,
                                                 const float* __restrict__ beta,
                                                 const float* __restrict__ part,
                                                 float* __restrict__ out) {
  __shared__ __align__(16) short As[64 * 32];
  __shared__ __align__(16) short Bs[128 * 32];
  __shared__ float sstats[32];
  int m0 = blockIdx.x * 64, n0 = blockIdx.y * 128, b = blockIdx.z;
  const short* A = ao + (long)b * 4096 * 256;
  int t = threadIdx.x, wv = t >> 6, lane = t & 63, lg = lane >> 4, lq = lane & 15;
  int wr = wv >> 1, wc = wv & 1;
  stats_prologue(part, sstats, t);
  f32x4 acc[2][4] = {};
  for (int kt = 0; kt < 8; kt++) {
    int k0 = kt * 32;
    {
      int row = t >> 2, kch = t & 3;
      int kk = kch ^ ((row >> 1) & 3);
      gload16(A + (m0 + row) * 256 + k0 + kk * 8, &As[wv * 512]);
    }
#pragma unroll
    for (int it = 0; it < 2; it++) {
      int chunk = t + it * 256;
      int row = chunk >> 2, kch = chunk & 3;
      int kk = kch ^ ((row >> 1) & 3);
      gload16(wpb + (n0 + row) * 256 + k0 + kk * 8, &Bs[it * 2048 + wv * 512]);
    }
    __syncthreads();
    s16x8 af[2], bfr[4];
#pragma unroll
    for (int mi = 0; mi < 2; mi++) {
      int row = wr * 32 + mi * 16 + lq;
      af[mi] = *(const s16x8*)&As[row * 32 + ((lg ^ ((row >> 1) & 3)) << 3)];
    }
#pragma unroll
    for (int ni = 0; ni < 4; ni++) {
      int row = wc * 64 + ni * 16 + lq;
      bfr[ni] = *(const s16x8*)&Bs[row * 32 + ((lg ^ ((row >> 1) & 3)) << 3)];
    }
#pragma unroll
    for (int mi = 0; mi < 2; mi++)
#pragma unroll
      for (int ni = 0; ni < 4; ni++)
        acc[mi][ni] = MFMA16(af[mi], bfr[ni], acc[mi][ni]);
    __syncthreads();
  }
#pragma unroll
  for (int mi = 0; mi < 2; mi++)
#pragma unroll
    for (int ni = 0; ni < 4; ni++) {
      int p = m0 + wr * 32 + mi * 16 + (lg << 2);
      int o = n0 + wc * 64 + ni * 16 + lq;
      int g = b * 8 + (o >> 5);
      float mean = sstats[g * 2], rstd = sstats[g * 2 + 1];
      float ga = gamma[o] * rstd;
      float be = beta[o] - mean * ga + bproj[o];
      long idx = ((long)(b * 256 + o)) * 4096 + p;
      float4 xv = *(const float4*)(x + idx);
      float4 ov = {acc[mi][ni][0] + xv.x * ga + be, acc[mi][ni][1] + xv.y * ga + be,
                   acc[mi][ni][2] + xv.z * ga + be, acc[mi][ni][3] + xv.w * ga + be};
      *(float4*)(out + idx) = ov;
    }
}

// ---------------------------------------------------------------------------
extern "C" void kernel_launch(void* const* d_in, const int* in_sizes, int n_in,
                              void* d_out, int out_size, void* d_ws, size_t ws_size,
                              hipStream_t stream) {
  const float* x = (const float*)d_in[0];
  const float* gamma = (const float*)d_in[1];
  const float* beta = (const float*)d_in[2];
  const float* wq = (const float*)d_in[3];
  const float* wp = (const float*)d_in[4];
  const float* bp = (const float*)d_in[5];
  float* out = (float*)d_out;
  char* ws = (char*)d_ws;

  short* xnT = (short*)(ws + 0);                //  4 MB  bf16 (b,p,c)
  short* wqb = (short*)(ws + 4194304);          //  384KB
  short* wpb = (short*)(ws + 4587520);          //  128KB
  short* qT = (short*)(ws + 4718592);           //  4 MB  bf16 (b,p,256) Q
  short* kP = (short*)(ws + 8912896);           //  4 MB  bf16 fragged K
  short* vP = (short*)(ws + 13107200);          //  4 MB  bf16 fragged V
  short* ao = (short*)(ws + 17301504);          //  4 MB  bf16 (b,p,C)
  float* gpart = (float*)(ws + 21495808);       //  2 KB

  pre_gn<<<1280, 256, 0, stream>>>(x, wq, wp, wqb, wpb, gpart);
  gn_norm_t<<<512, 256, 0, stream>>>(x, gamma, beta, gpart, xnT);
  qkv_gemm<<<dim3(64, 6, 2), 256, 0, stream>>>(xnT, wqb, qT, kP, vP);
  attn<<<512, 256, 0, stream>>>(qT, kP, vP, ao);
  proj_gemm<<<dim3(64, 2, 2), 256, 0, stream>>>(ao, wpb, bp, x, gamma, beta, gpart, out);
}

// Round 13
// 68.597 us; speedup vs baseline: 1.5213x; 1.5213x over previous
//
#include <hip/hip_runtime.h>

// ---------------------------------------------------------------------------
// AttentionBlock: GN(8 groups) -> QKV(768x256) -> 4-head attn (HW=4096, d=64)
//                 -> proj(256x256)+bias -> +xn residual.   B=2, C=256.
// R13: attn reverted to R11-exact (2-deep ping-pong; R12's 3-deep spilled).
//  - qkv Q-epilogue now goes through the LDS transpose -> coalesced 16B
//    stores (was 4x scalar 2B at 512B stride).
//  - proj_gemm M-tile 32 -> grid 512 = 2 blocks/CU (was 1).
// ---------------------------------------------------------------------------

typedef short s16x8 __attribute__((ext_vector_type(8)));
typedef float f32x4 __attribute__((ext_vector_type(4)));

#define MFMA16(a, b, c) __builtin_amdgcn_mfma_f32_16x16x32_bf16(a, b, c, 0, 0, 0)

__device__ __forceinline__ short bf16s(float f) {
  union { float f; unsigned u; } v; v.f = f;
  unsigned r = v.u + 0x7fffu + ((v.u >> 16) & 1u);
  return (short)(r >> 16);
}

__device__ __forceinline__ unsigned cvtpk(float lo, float hi) {
  unsigned r;
  asm("v_cvt_pk_bf16_f32 %0, %1, %2" : "=v"(r) : "v"(lo), "v"(hi));
  return r;
}

// 2^x via single v_exp_f32 (hazard-safe builtin). |x| < ~30 in this kernel.
__device__ __forceinline__ float exp_raw(float x) {
  return __builtin_amdgcn_exp2f(x);
}

__device__ __forceinline__ void gload16(const void* g, void* l) {
  __builtin_amdgcn_global_load_lds(
      (const __attribute__((address_space(1))) unsigned*)g,
      (__attribute__((address_space(3))) unsigned*)l, 16, 0, 0);
}

// ---------------- K1: GN partial sums (blk<256) + weight->bf16 (blk>=256) ---
__global__ __launch_bounds__(256) void pre_gn(const float* __restrict__ x,
                                              const float* __restrict__ wq,
                                              const float* __restrict__ wp,
                                              short* __restrict__ wqb,
                                              short* __restrict__ wpb,
                                              float* __restrict__ part) {
  int blk = blockIdx.x;
  int t = threadIdx.x;
  if (blk >= 256) {  // ---- weights -> bf16 ----
    int i = (blk - 256) * 256 + t;
    if (i < 768 * 256) {
      wqb[i] = bf16s(wq[i]);
    } else {
      int j = i - 768 * 256;
      if (j < 256 * 256) wpb[j] = bf16s(wp[j]);
    }
    return;
  }
  // ---- GN partial sums (16 groups x 16 parts) ----
  int gi = blk >> 4, sub = blk & 15;
  const float* base = x + (long)gi * 131072 + sub * 8192;
  float s = 0.f, ss = 0.f;
#pragma unroll
  for (int k = 0; k < 8; k++) {
    float4 v = *(const float4*)(base + t * 4 + k * 1024);
    s += v.x + v.y + v.z + v.w;
    ss += v.x * v.x + v.y * v.y + v.z * v.z + v.w * v.w;
  }
#pragma unroll
  for (int m = 1; m < 64; m <<= 1) { s += __shfl_xor(s, m); ss += __shfl_xor(ss, m); }
  __shared__ float red[8];
  int wv = t >> 6;
  if ((t & 63) == 0) { red[wv * 2] = s; red[wv * 2 + 1] = ss; }
  __syncthreads();
  if (t == 0) {
    float S = 0.f, SS = 0.f;
    for (int w = 0; w < 4; w++) { S += red[w * 2]; SS += red[w * 2 + 1]; }
    part[blk * 2] = S; part[blk * 2 + 1] = SS;
  }
}

// stats-from-partials prologue (16 groups; g = b*8 + c/32)
__device__ __forceinline__ void stats_prologue(const float* __restrict__ part,
                                               float* sstats, int t) {
  if (t < 16) {
    float S = 0.f, SS = 0.f;
#pragma unroll
    for (int i = 0; i < 16; i++) {
      S += part[(t * 16 + i) * 2];
      SS += part[(t * 16 + i) * 2 + 1];
    }
    float mean = S * (1.0f / 131072.0f);
    float var = SS * (1.0f / 131072.0f) - mean * mean;
    sstats[t * 2] = mean;
    sstats[t * 2 + 1] = rsqrtf(var + 1e-5f);
  }
}

// ---------------- K2: normalize + transpose -> xnT bf16 (p,c) --------------
__global__ __launch_bounds__(256) void gn_norm_t(const float* __restrict__ x,
                                                 const float* __restrict__ gamma,
                                                 const float* __restrict__ beta,
                                                 const float* __restrict__ part,
                                                 short* __restrict__ xnT) {
  __shared__ __align__(16) short T[64 * 88];
  __shared__ float sstats[32];
  int bx = blockIdx.x;
  int pt = bx & 63, ct = (bx >> 6) & 3, b = bx >> 8;
  int t = threadIdx.x;
  stats_prologue(part, sstats, t);
  __syncthreads();
#pragma unroll
  for (int it = 0; it < 4; it++) {
    int chunk = t + it * 256;
    int c_loc = chunk >> 4, pch = chunk & 15;
    int c = ct * 64 + c_loc;
    int g = b * 8 + (c >> 5);
    float mean = sstats[g * 2], rstd = sstats[g * 2 + 1];
    float ga = gamma[c] * rstd;
    float be = beta[c] - mean * ga;
    long idx = ((long)(b * 256 + c)) * 4096 + pt * 64 + pch * 4;
    float4 v = *(const float4*)(x + idx);
    float4 n = {v.x * ga + be, v.y * ga + be, v.z * ga + be, v.w * ga + be};
    int p0 = pch * 4;
    T[(p0 + 0) * 88 + c_loc] = bf16s(n.x);
    T[(p0 + 1) * 88 + c_loc] = bf16s(n.y);
    T[(p0 + 2) * 88 + c_loc] = bf16s(n.z);
    T[(p0 + 3) * 88 + c_loc] = bf16s(n.w);
  }
  __syncthreads();
#pragma unroll
  for (int it = 0; it < 2; it++) {
    int chunk = t + it * 256;
    int p_loc = chunk >> 3, cch = chunk & 7;
    s16x8 v = *(const s16x8*)&T[p_loc * 88 + cch * 8];
    *(s16x8*)&xnT[((long)(b * 4096 + pt * 64 + p_loc)) * 256 + ct * 64 + cch * 8] = v;
  }
}

// ---------------- K3: QKV TN-GEMM, M-tile 64 --------------------------------
// D[p,o] = xnT[p,:] . wq[o,:].
//   y<2: Q (scaled 0.125*log2 e) -> qT via LDS transpose, coalesced stores
//   y in {2,3}: K -> kP via LDS transpose, coalesced 16B stores
//   y in {4,5}: V -> vP (u64 stores)
__global__ __launch_bounds__(256) void qkv_gemm(const short* __restrict__ xnT,
                                                const short* __restrict__ wqb,
                                                short* __restrict__ qT,
                                                short* __restrict__ kP,
                                                short* __restrict__ vP) {
  __shared__ __align__(16) short smem[8320];  // As(2048)+Bs(4096) | Ts 64x130
  short* As = smem;
  short* Bs = smem + 2048;
  int m0 = blockIdx.x * 64, n0 = blockIdx.y * 128, b = blockIdx.z;
  const short* A = xnT + (long)b * 4096 * 256;
  int t = threadIdx.x, wv = t >> 6, lane = t & 63, lg = lane >> 4, lq = lane & 15;
  int wr = wv >> 1, wc = wv & 1;
  f32x4 acc[2][4] = {};
  for (int kt = 0; kt < 8; kt++) {
    int k0 = kt * 32;
    {
      int row = t >> 2, kch = t & 3;
      int kk = kch ^ ((row >> 1) & 3);
      gload16(A + (m0 + row) * 256 + k0 + kk * 8, &As[wv * 512]);
    }
#pragma unroll
    for (int it = 0; it < 2; it++) {
      int chunk = t + it * 256;
      int row = chunk >> 2, kch = chunk & 3;
      int kk = kch ^ ((row >> 1) & 3);
      gload16(wqb + (n0 + row) * 256 + k0 + kk * 8, &Bs[it * 2048 + wv * 512]);
    }
    __syncthreads();
    s16x8 af[2], bfr[4];
#pragma unroll
    for (int mi = 0; mi < 2; mi++) {
      int row = wr * 32 + mi * 16 + lq;
      af[mi] = *(const s16x8*)&As[row * 32 + ((lg ^ ((row >> 1) & 3)) << 3)];
    }
#pragma unroll
    for (int ni = 0; ni < 4; ni++) {
      int row = wc * 64 + ni * 16 + lq;
      bfr[ni] = *(const s16x8*)&Bs[row * 32 + ((lg ^ ((row >> 1) & 3)) << 3)];
    }
#pragma unroll
    for (int mi = 0; mi < 2; mi++)
#pragma unroll
      for (int ni = 0; ni < 4; ni++)
        acc[mi][ni] = MFMA16(af[mi], bfr[ni], acc[mi][ni]);
    __syncthreads();
  }
  if (blockIdx.y < 2) {  // ---- Q: LDS transpose -> coalesced qT stores ----
    short(*Ts)[130] = (short(*)[130])smem;
#pragma unroll
    for (int mi = 0; mi < 2; mi++)
#pragma unroll
      for (int ni = 0; ni < 4; ni++) {
        int pr = wr * 32 + mi * 16 + (lg << 2);
        int oc = wc * 64 + ni * 16 + lq;
#pragma unroll
        for (int r = 0; r < 4; r++)
          Ts[pr + r][oc] = bf16s(acc[mi][ni][r] * 0.180336880f);
      }
    __syncthreads();
    short* Out = qT + (long)b * 4096 * 256;
#pragma unroll
    for (int it = 0; it < 4; it++) {
      int chunk = t + it * 256;
      int row = chunk >> 4, cc8 = (chunk & 15) * 8;
      s16x8 v = *(const s16x8*)&Ts[row][cc8];
      *(s16x8*)&Out[(long)(m0 + row) * 256 + n0 + cc8] = v;
    }
  } else if (blockIdx.y < 4) {  // ---- K: LDS transpose -> coalesced kP ----
    short(*Ts)[130] = (short(*)[130])smem;
#pragma unroll
    for (int mi = 0; mi < 2; mi++)
#pragma unroll
      for (int ni = 0; ni < 4; ni++) {
        int pr = wr * 32 + mi * 16 + (lg << 2);
        int oc = wc * 64 + ni * 16 + lq;
#pragma unroll
        for (int r = 0; r < 4; r++) Ts[pr + r][oc] = bf16s(acc[mi][ni][r]);
      }
    __syncthreads();
    int reg = t >> 6;
    int tl = reg >> 1, hl = reg & 1;
    int l2 = t & 63, lq2 = l2 & 15, lg2 = l2 >> 4;
    int hb = (n0 - 256) >> 6;
    long kb2 = ((long)(b * 4 + hb + hl) * 128 + (m0 >> 5) + tl) * 2048;
#pragma unroll
    for (int f = 0; f < 4; f++) {
      int row = 32 * tl + (lq2 & 3) + 8 * (lq2 >> 2) + 4 * (f >> 1);  // pi(lq2)
      int col = hl * 64 + 32 * (f & 1) + 8 * lg2;
      s16x8 v = *(const s16x8*)&Ts[row][col];
      *(s16x8*)&kP[kb2 + f * 512 + l2 * 8] = v;
    }
  } else {  // ---- V -> vP ----
#pragma unroll
    for (int mi = 0; mi < 2; mi++)
#pragma unroll
      for (int ni = 0; ni < 4; ni++) {
        int p = m0 + wr * 32 + mi * 16 + (lg << 2);
        int c = (n0 - 512) + wc * 64 + ni * 16 + lq;
        int h = c >> 6, ch = c & 63;
        int f = ch >> 4, lqp = ch & 15;
        int tile = p >> 5, lgp = (p & 31) >> 3, e0 = p & 7;
        unsigned u0 = cvtpk(acc[mi][ni][0], acc[mi][ni][1]);
        unsigned u1 = cvtpk(acc[mi][ni][2], acc[mi][ni][3]);
        *(unsigned long long*)&vP[((long)(b * 4 + h) * 128 + tile) * 2048 +
                                  f * 512 + (lgp * 16 + lqp) * 8 + e0] =
            ((unsigned long long)u1 << 32) | u0;
      }
  }
}

// ---------------- K4: flash attention (R11-exact, 2-deep ping-pong) --------
#define LOADKV(KF, VF, JT)                                                  \
  do {                                                                      \
    long tb_ = ((long)((JT) * 4 + wv)) * 2048 + l * 8;                      \
    KF##0 = *(const s16x8*)(kp + tb_);                                      \
    KF##1 = *(const s16x8*)(kp + tb_ + 512);                                \
    KF##2 = *(const s16x8*)(kp + tb_ + 1024);                               \
    KF##3 = *(const s16x8*)(kp + tb_ + 1536);                               \
    VF##0 = *(const s16x8*)(vp + tb_);                                      \
    VF##1 = *(const s16x8*)(vp + tb_ + 512);                                \
    VF##2 = *(const s16x8*)(vp + tb_ + 1024);                               \
    VF##3 = *(const s16x8*)(vp + tb_ + 1536);                               \
  } while (0)

#define COMPUTE(KF, VF)                                                     \
  do {                                                                      \
    _Pragma("unroll") for (int ig = 0; ig < 4; ig++) {                      \
      f32x4 z0 = {0.f, 0.f, 0.f, 0.f}, z1 = {0.f, 0.f, 0.f, 0.f};           \
      z0 = MFMA16(KF##0, qf[ig][0], z0);                                    \
      z0 = MFMA16(KF##1, qf[ig][1], z0);                                    \
      z1 = MFMA16(KF##2, qf[ig][0], z1);                                    \
      z1 = MFMA16(KF##3, qf[ig][1], z1);                                    \
      f32x4 p0, p1;                                                         \
      _Pragma("unroll") for (int r = 0; r < 4; r++) {                       \
        p0[r] = exp_raw(z0[r]);                                             \
        p1[r] = exp_raw(z1[r]);                                             \
      }                                                                     \
      f32x4 ps = p0 + p1;                                                   \
      lsc[ig] += (ps[0] + ps[1]) + (ps[2] + ps[3]);                         \
      union { unsigned u[4]; s16x8 v; } pb;                                 \
      pb.u[0] = cvtpk(p0[0], p0[1]);                                        \
      pb.u[1] = cvtpk(p0[2], p0[3]);                                        \
      pb.u[2] = cvtpk(p1[0], p1[1]);                                        \
      pb.u[3] = cvtpk(p1[2], p1[3]);                                        \
      oacc[ig][0] = MFMA16(VF##0, pb.v, oacc[ig][0]);                       \
      oacc[ig][1] = MFMA16(VF##1, pb.v, oacc[ig][1]);                       \
      oacc[ig][2] = MFMA16(VF##2, pb.v, oacc[ig][2]);                       \
      oacc[ig][3] = MFMA16(VF##3, pb.v, oacc[ig][3]);                       \
    }                                                                       \
  } while (0)

__global__ __launch_bounds__(256, 2) void attn(const short* __restrict__ qT_,
                                               const short* __restrict__ kP,
                                               const short* __restrict__ vP,
                                               short* __restrict__ ao_) {
  __shared__ __align__(16) f32x4 cb[2 * 1088];  // 2 regions x 17 items x 64 lanes
  int bid = blockIdx.x;
  int bh = bid & 7, itile = bid >> 3;  // bh -> XCD (round-robin)
  int b = bh >> 2, h = bh & 3;
  int i0 = itile * 64;
  const short* kp = kP + (long)bh * 128 * 2048;
  const short* vp = vP + (long)bh * 128 * 2048;
  short* ao = ao_ + (long)b * 4096 * 256;
  int t = threadIdx.x, wv = t >> 6, l = t & 63, lq = l & 15, lg = l >> 4;

  // Q fragments, resident for the whole kernel
  s16x8 qf[4][2];
  const short* qbase = qT_ + (long)b * 4096 * 256 + h * 64;
#pragma unroll
  for (int ig = 0; ig < 4; ig++) {
    const short* qr = qbase + (long)(i0 + ig * 16 + lq) * 256;
    qf[ig][0] = *(const s16x8*)(qr + 8 * lg);
    qf[ig][1] = *(const s16x8*)(qr + 32 + 8 * lg);
  }

  f32x4 oacc[4][4] = {};
  float lsc[4] = {0.f, 0.f, 0.f, 0.f};

  s16x8 ka0, ka1, ka2, ka3, va0, va1, va2, va3;
  s16x8 kb0, kb1, kb2, kb3, vb0, vb1, vb2, vb3;

  LOADKV(ka, va, 0);
  for (int jt = 0; jt < 32; jt += 2) {
    LOADKV(kb, vb, jt + 1);
    COMPUTE(ka, va);
    if (jt + 2 < 32) LOADKV(ka, va, jt + 2);
    COMPUTE(kb, vb);
  }

  // ---- l: cross-lg reduce (i = lq lane-local) ----
  f32x4 lv4;
#pragma unroll
  for (int ig = 0; ig < 4; ig++) {
    float s = lsc[ig];
    s += __shfl_xor(s, 16);
    s += __shfl_xor(s, 32);
    lv4[ig] = s;
  }

  // ---- 2-round cross-wave combine tree ----
#define CB_W(REG)                                                           \
  do {                                                                      \
    f32x4* d_ = cb + (REG) * 1088;                                          \
    _Pragma("unroll") for (int ig = 0; ig < 4; ig++)                        \
    _Pragma("unroll") for (int nc = 0; nc < 4; nc++)                        \
        d_[(ig * 4 + nc) * 64 + l] = oacc[ig][nc];                          \
    d_[16 * 64 + l] = lv4;                                                  \
  } while (0)
#define CB_A(REG)                                                           \
  do {                                                                      \
    f32x4* s_ = cb + (REG) * 1088;                                          \
    _Pragma("unroll") for (int ig = 0; ig < 4; ig++)                        \
    _Pragma("unroll") for (int nc = 0; nc < 4; nc++)                        \
        oacc[ig][nc] += s_[(ig * 4 + nc) * 64 + l];                         \
    lv4 += s_[16 * 64 + l];                                                 \
  } while (0)

  if (wv >= 2) CB_W(wv - 2);
  __syncthreads();
  if (wv < 2) CB_A(wv);
  __syncthreads();
  if (wv == 1) CB_W(0);
  __syncthreads();
  if (wv == 0) {
    CB_A(0);
#pragma unroll
    for (int ig = 0; ig < 4; ig++) {
      float inv = 1.0f / lv4[ig];
      long irow = i0 + ig * 16 + lq;
#pragma unroll
      for (int nc = 0; nc < 4; nc++) {
        f32x4 o = oacc[ig][nc];
        unsigned u0 = cvtpk(o[0] * inv, o[1] * inv);
        unsigned u1 = cvtpk(o[2] * inv, o[3] * inv);
        *(unsigned long long*)&ao[irow * 256 + h * 64 + nc * 16 + 4 * lg] =
            ((unsigned long long)u1 << 32) | u0;
      }
    }
  }
}

// ---------------- K5: proj TN-GEMM (M-tile 32) + bias + GN residual --------
__global__ __launch_bounds__(256) void proj_gemm(const short* __restrict__ ao,
                                                 const short* __restrict__ wpb,
                                                 const float* __restrict__ bproj,
                                                 const float* __restrict__ x,
                                                 const float* __restrict__ gamma,
                                                 const float* __restrict__ beta,
                                                 const float* __restrict__ part,
                                                 float* __restrict__ out) {
  __shared__ __align__(16) short As[32 * 32];
  __shared__ __align__(16) short Bs[128 * 32];
  __shared__ float sstats[32];
  int m0 = blockIdx.x * 32, n0 = blockIdx.y * 128, b = blockIdx.z;
  const short* A = ao + (long)b * 4096 * 256;
  int t = threadIdx.x, wv = t >> 6, lane = t & 63, lg = lane >> 4, lq = lane & 15;
  int wr = wv >> 1, wc = wv & 1;
  stats_prologue(part, sstats, t);
  f32x4 acc[4] = {};
  for (int kt = 0; kt < 8; kt++) {
    int k0 = kt * 32;
    if (t < 128) {
      int row = t >> 2, kch = t & 3;
      int kk = kch ^ ((row >> 1) & 3);
      gload16(A + (m0 + row) * 256 + k0 + kk * 8, &As[wv * 512]);
    }
#pragma unroll
    for (int it = 0; it < 2; it++) {
      int chunk = t + it * 256;
      int row = chunk >> 2, kch = chunk & 3;
      int kk = kch ^ ((row >> 1) & 3);
      gload16(wpb + (n0 + row) * 256 + k0 + kk * 8, &Bs[it * 2048 + wv * 512]);
    }
    __syncthreads();
    s16x8 af, bfr[4];
    {
      int row = wr * 16 + lq;
      af = *(const s16x8*)&As[row * 32 + ((lg ^ ((row >> 1) & 3)) << 3)];
    }
#pragma unroll
    for (int ni = 0; ni < 4; ni++) {
      int row = wc * 64 + ni * 16 + lq;
      bfr[ni] = *(const s16x8*)&Bs[row * 32 + ((lg ^ ((row >> 1) & 3)) << 3)];
    }
#pragma unroll
    for (int ni = 0; ni < 4; ni++) acc[ni] = MFMA16(af, bfr[ni], acc[ni]);
    __syncthreads();
  }
#pragma unroll
  for (int ni = 0; ni < 4; ni++) {
    int p = m0 + wr * 16 + (lg << 2);
    int o = n0 + wc * 64 + ni * 16 + lq;
    int g = b * 8 + (o >> 5);
    float mean = sstats[g * 2], rstd = sstats[g * 2 + 1];
    float ga = gamma[o] * rstd;
    float be = beta[o] - mean * ga + bproj[o];
    long idx = ((long)(b * 256 + o)) * 4096 + p;
    float4 xv = *(const float4*)(x + idx);
    float4 ov = {acc[ni][0] + xv.x * ga + be, acc[ni][1] + xv.y * ga + be,
                 acc[ni][2] + xv.z * ga + be, acc[ni][3] + xv.w * ga + be};
    *(float4*)(out + idx) = ov;
  }
}

// ---------------------------------------------------------------------------
extern "C" void kernel_launch(void* const* d_in, const int* in_sizes, int n_in,
                              void* d_out, int out_size, void* d_ws, size_t ws_size,
                              hipStream_t stream) {
  const float* x = (const float*)d_in[0];
  const float* gamma = (const float*)d_in[1];
  const float* beta = (const float*)d_in[2];
  const float* wq = (const float*)d_in[3];
  const float* wp = (const float*)d_in[4];
  const float* bp = (const float*)d_in[5];
  float* out = (float*)d_out;
  char* ws = (char*)d_ws;

  short* xnT = (short*)(ws + 0);                //  4 MB  bf16 (b,p,c)
  short* wqb = (short*)(ws + 4194304);          //  384KB
  short* wpb = (short*)(ws + 4587520);          //  128KB
  short* qT = (short*)(ws + 4718592);           //  4 MB  bf16 (b,p,256) Q
  short* kP = (short*)(ws + 8912896);           //  4 MB  bf16 fragged K
  short* vP = (short*)(ws + 13107200);          //  4 MB  bf16 fragged V
  short* ao = (short*)(ws + 17301504);          //  4 MB  bf16 (b,p,C)
  float* gpart = (float*)(ws + 21495808);       //  2 KB

  pre_gn<<<1280, 256, 0, stream>>>(x, wq, wp, wqb, wpb, gpart);
  gn_norm_t<<<512, 256, 0, stream>>>(x, gamma, beta, gpart, xnT);
  qkv_gemm<<<dim3(64, 6, 2), 256, 0, stream>>>(xnT, wqb, qT, kP, vP);
  attn<<<512, 256, 0, stream>>>(qT, kP, vP, ao);
  proj_gemm<<<dim3(128, 2, 2), 256, 0, stream>>>(ao, wpb, bp, x, gamma, beta, gpart, out);
}

// Round 14
// 67.146 us; speedup vs baseline: 1.5542x; 1.0216x over previous
//
#include <hip/hip_runtime.h>

// ---------------------------------------------------------------------------
// AttentionBlock: GN(8 groups) -> QKV(768x256) -> 4-head attn (HW=4096, d=64)
//                 -> proj(256x256)+bias -> +xn residual.   B=2, C=256.
// R14: isolated change vs R13 — attn's l-sum moves from VALU to the MFMA
// pipe: lacc[ig] = mfma(ones, pb, lacc[ig]) sums P over k=32 (both lg
// halves) per i-column; kills ~28 VALU ops/jt + the epilogue shuffle pair.
// MFMA pipe has 68% idle headroom; VALU was the busier pipe (39%).
// ---------------------------------------------------------------------------

typedef short s16x8 __attribute__((ext_vector_type(8)));
typedef float f32x4 __attribute__((ext_vector_type(4)));

#define MFMA16(a, b, c) __builtin_amdgcn_mfma_f32_16x16x32_bf16(a, b, c, 0, 0, 0)

__device__ __forceinline__ short bf16s(float f) {
  union { float f; unsigned u; } v; v.f = f;
  unsigned r = v.u + 0x7fffu + ((v.u >> 16) & 1u);
  return (short)(r >> 16);
}

__device__ __forceinline__ unsigned cvtpk(float lo, float hi) {
  unsigned r;
  asm("v_cvt_pk_bf16_f32 %0, %1, %2" : "=v"(r) : "v"(lo), "v"(hi));
  return r;
}

// 2^x via single v_exp_f32 (hazard-safe builtin). |x| < ~30 in this kernel.
__device__ __forceinline__ float exp_raw(float x) {
  return __builtin_amdgcn_exp2f(x);
}

__device__ __forceinline__ void gload16(const void* g, void* l) {
  __builtin_amdgcn_global_load_lds(
      (const __attribute__((address_space(1))) unsigned*)g,
      (__attribute__((address_space(3))) unsigned*)l, 16, 0, 0);
}

// ---------------- K1: GN partial sums (blk<256) + weight->bf16 (blk>=256) ---
__global__ __launch_bounds__(256) void pre_gn(const float* __restrict__ x,
                                              const float* __restrict__ wq,
                                              const float* __restrict__ wp,
                                              short* __restrict__ wqb,
                                              short* __restrict__ wpb,
                                              float* __restrict__ part) {
  int blk = blockIdx.x;
  int t = threadIdx.x;
  if (blk >= 256) {  // ---- weights -> bf16 ----
    int i = (blk - 256) * 256 + t;
    if (i < 768 * 256) {
      wqb[i] = bf16s(wq[i]);
    } else {
      int j = i - 768 * 256;
      if (j < 256 * 256) wpb[j] = bf16s(wp[j]);
    }
    return;
  }
  // ---- GN partial sums (16 groups x 16 parts) ----
  int gi = blk >> 4, sub = blk & 15;
  const float* base = x + (long)gi * 131072 + sub * 8192;
  float s = 0.f, ss = 0.f;
#pragma unroll
  for (int k = 0; k < 8; k++) {
    float4 v = *(const float4*)(base + t * 4 + k * 1024);
    s += v.x + v.y + v.z + v.w;
    ss += v.x * v.x + v.y * v.y + v.z * v.z + v.w * v.w;
  }
#pragma unroll
  for (int m = 1; m < 64; m <<= 1) { s += __shfl_xor(s, m); ss += __shfl_xor(ss, m); }
  __shared__ float red[8];
  int wv = t >> 6;
  if ((t & 63) == 0) { red[wv * 2] = s; red[wv * 2 + 1] = ss; }
  __syncthreads();
  if (t == 0) {
    float S = 0.f, SS = 0.f;
    for (int w = 0; w < 4; w++) { S += red[w * 2]; SS += red[w * 2 + 1]; }
    part[blk * 2] = S; part[blk * 2 + 1] = SS;
  }
}

// stats-from-partials prologue (16 groups; g = b*8 + c/32)
__device__ __forceinline__ void stats_prologue(const float* __restrict__ part,
                                               float* sstats, int t) {
  if (t < 16) {
    float S = 0.f, SS = 0.f;
#pragma unroll
    for (int i = 0; i < 16; i++) {
      S += part[(t * 16 + i) * 2];
      SS += part[(t * 16 + i) * 2 + 1];
    }
    float mean = S * (1.0f / 131072.0f);
    float var = SS * (1.0f / 131072.0f) - mean * mean;
    sstats[t * 2] = mean;
    sstats[t * 2 + 1] = rsqrtf(var + 1e-5f);
  }
}

// ---------------- K2: normalize + transpose -> xnT bf16 (p,c) --------------
__global__ __launch_bounds__(256) void gn_norm_t(const float* __restrict__ x,
                                                 const float* __restrict__ gamma,
                                                 const float* __restrict__ beta,
                                                 const float* __restrict__ part,
                                                 short* __restrict__ xnT) {
  __shared__ __align__(16) short T[64 * 88];
  __shared__ float sstats[32];
  int bx = blockIdx.x;
  int pt = bx & 63, ct = (bx >> 6) & 3, b = bx >> 8;
  int t = threadIdx.x;
  stats_prologue(part, sstats, t);
  __syncthreads();
#pragma unroll
  for (int it = 0; it < 4; it++) {
    int chunk = t + it * 256;
    int c_loc = chunk >> 4, pch = chunk & 15;
    int c = ct * 64 + c_loc;
    int g = b * 8 + (c >> 5);
    float mean = sstats[g * 2], rstd = sstats[g * 2 + 1];
    float ga = gamma[c] * rstd;
    float be = beta[c] - mean * ga;
    long idx = ((long)(b * 256 + c)) * 4096 + pt * 64 + pch * 4;
    float4 v = *(const float4*)(x + idx);
    float4 n = {v.x * ga + be, v.y * ga + be, v.z * ga + be, v.w * ga + be};
    int p0 = pch * 4;
    T[(p0 + 0) * 88 + c_loc] = bf16s(n.x);
    T[(p0 + 1) * 88 + c_loc] = bf16s(n.y);
    T[(p0 + 2) * 88 + c_loc] = bf16s(n.z);
    T[(p0 + 3) * 88 + c_loc] = bf16s(n.w);
  }
  __syncthreads();
#pragma unroll
  for (int it = 0; it < 2; it++) {
    int chunk = t + it * 256;
    int p_loc = chunk >> 3, cch = chunk & 7;
    s16x8 v = *(const s16x8*)&T[p_loc * 88 + cch * 8];
    *(s16x8*)&xnT[((long)(b * 4096 + pt * 64 + p_loc)) * 256 + ct * 64 + cch * 8] = v;
  }
}

// ---------------- K3: QKV TN-GEMM, M-tile 64 --------------------------------
__global__ __launch_bounds__(256) void qkv_gemm(const short* __restrict__ xnT,
                                                const short* __restrict__ wqb,
                                                short* __restrict__ qT,
                                                short* __restrict__ kP,
                                                short* __restrict__ vP) {
  __shared__ __align__(16) short smem[8320];  // As(2048)+Bs(4096) | Ts 64x130
  short* As = smem;
  short* Bs = smem + 2048;
  int m0 = blockIdx.x * 64, n0 = blockIdx.y * 128, b = blockIdx.z;
  const short* A = xnT + (long)b * 4096 * 256;
  int t = threadIdx.x, wv = t >> 6, lane = t & 63, lg = lane >> 4, lq = lane & 15;
  int wr = wv >> 1, wc = wv & 1;
  f32x4 acc[2][4] = {};
  for (int kt = 0; kt < 8; kt++) {
    int k0 = kt * 32;
    {
      int row = t >> 2, kch = t & 3;
      int kk = kch ^ ((row >> 1) & 3);
      gload16(A + (m0 + row) * 256 + k0 + kk * 8, &As[wv * 512]);
    }
#pragma unroll
    for (int it = 0; it < 2; it++) {
      int chunk = t + it * 256;
      int row = chunk >> 2, kch = chunk & 3;
      int kk = kch ^ ((row >> 1) & 3);
      gload16(wqb + (n0 + row) * 256 + k0 + kk * 8, &Bs[it * 2048 + wv * 512]);
    }
    __syncthreads();
    s16x8 af[2], bfr[4];
#pragma unroll
    for (int mi = 0; mi < 2; mi++) {
      int row = wr * 32 + mi * 16 + lq;
      af[mi] = *(const s16x8*)&As[row * 32 + ((lg ^ ((row >> 1) & 3)) << 3)];
    }
#pragma unroll
    for (int ni = 0; ni < 4; ni++) {
      int row = wc * 64 + ni * 16 + lq;
      bfr[ni] = *(const s16x8*)&Bs[row * 32 + ((lg ^ ((row >> 1) & 3)) << 3)];
    }
#pragma unroll
    for (int mi = 0; mi < 2; mi++)
#pragma unroll
      for (int ni = 0; ni < 4; ni++)
        acc[mi][ni] = MFMA16(af[mi], bfr[ni], acc[mi][ni]);
    __syncthreads();
  }
  if (blockIdx.y < 2) {  // ---- Q: LDS transpose -> coalesced qT stores ----
    short(*Ts)[130] = (short(*)[130])smem;
#pragma unroll
    for (int mi = 0; mi < 2; mi++)
#pragma unroll
      for (int ni = 0; ni < 4; ni++) {
        int pr = wr * 32 + mi * 16 + (lg << 2);
        int oc = wc * 64 + ni * 16 + lq;
#pragma unroll
        for (int r = 0; r < 4; r++)
          Ts[pr + r][oc] = bf16s(acc[mi][ni][r] * 0.180336880f);
      }
    __syncthreads();
    short* Out = qT + (long)b * 4096 * 256;
#pragma unroll
    for (int it = 0; it < 4; it++) {
      int chunk = t + it * 256;
      int row = chunk >> 4, cc8 = (chunk & 15) * 8;
      s16x8 v = *(const s16x8*)&Ts[row][cc8];
      *(s16x8*)&Out[(long)(m0 + row) * 256 + n0 + cc8] = v;
    }
  } else if (blockIdx.y < 4) {  // ---- K: LDS transpose -> coalesced kP ----
    short(*Ts)[130] = (short(*)[130])smem;
#pragma unroll
    for (int mi = 0; mi < 2; mi++)
#pragma unroll
      for (int ni = 0; ni < 4; ni++) {
        int pr = wr * 32 + mi * 16 + (lg << 2);
        int oc = wc * 64 + ni * 16 + lq;
#pragma unroll
        for (int r = 0; r < 4; r++) Ts[pr + r][oc] = bf16s(acc[mi][ni][r]);
      }
    __syncthreads();
    int reg = t >> 6;
    int tl = reg >> 1, hl = reg & 1;
    int l2 = t & 63, lq2 = l2 & 15, lg2 = l2 >> 4;
    int hb = (n0 - 256) >> 6;
    long kb2 = ((long)(b * 4 + hb + hl) * 128 + (m0 >> 5) + tl) * 2048;
#pragma unroll
    for (int f = 0; f < 4; f++) {
      int row = 32 * tl + (lq2 & 3) + 8 * (lq2 >> 2) + 4 * (f >> 1);  // pi(lq2)
      int col = hl * 64 + 32 * (f & 1) + 8 * lg2;
      s16x8 v = *(const s16x8*)&Ts[row][col];
      *(s16x8*)&kP[kb2 + f * 512 + l2 * 8] = v;
    }
  } else {  // ---- V -> vP ----
#pragma unroll
    for (int mi = 0; mi < 2; mi++)
#pragma unroll
      for (int ni = 0; ni < 4; ni++) {
        int p = m0 + wr * 32 + mi * 16 + (lg << 2);
        int c = (n0 - 512) + wc * 64 + ni * 16 + lq;
        int h = c >> 6, ch = c & 63;
        int f = ch >> 4, lqp = ch & 15;
        int tile = p >> 5, lgp = (p & 31) >> 3, e0 = p & 7;
        unsigned u0 = cvtpk(acc[mi][ni][0], acc[mi][ni][1]);
        unsigned u1 = cvtpk(acc[mi][ni][2], acc[mi][ni][3]);
        *(unsigned long long*)&vP[((long)(b * 4 + h) * 128 + tile) * 2048 +
                                  f * 512 + (lgp * 16 + lqp) * 8 + e0] =
            ((unsigned long long)u1 << 32) | u0;
      }
  }
}

// ---------------- K4: flash attention, l-sum via ones-MFMA ------------------
#define LOADKV(KF, VF, JT)                                                  \
  do {                                                                      \
    long tb_ = ((long)((JT) * 4 + wv)) * 2048 + l * 8;                      \
    KF##0 = *(const s16x8*)(kp + tb_);                                      \
    KF##1 = *(const s16x8*)(kp + tb_ + 512);                                \
    KF##2 = *(const s16x8*)(kp + tb_ + 1024);                               \
    KF##3 = *(const s16x8*)(kp + tb_ + 1536);                               \
    VF##0 = *(const s16x8*)(vp + tb_);                                      \
    VF##1 = *(const s16x8*)(vp + tb_ + 512);                                \
    VF##2 = *(const s16x8*)(vp + tb_ + 1024);                               \
    VF##3 = *(const s16x8*)(vp + tb_ + 1536);                               \
  } while (0)

#define COMPUTE(KF, VF)                                                     \
  do {                                                                      \
    _Pragma("unroll") for (int ig = 0; ig < 4; ig++) {                      \
      f32x4 z0 = {0.f, 0.f, 0.f, 0.f}, z1 = {0.f, 0.f, 0.f, 0.f};           \
      z0 = MFMA16(KF##0, qf[ig][0], z0);                                    \
      z0 = MFMA16(KF##1, qf[ig][1], z0);                                    \
      z1 = MFMA16(KF##2, qf[ig][0], z1);                                    \
      z1 = MFMA16(KF##3, qf[ig][1], z1);                                    \
      f32x4 p0, p1;                                                         \
      _Pragma("unroll") for (int r = 0; r < 4; r++) {                       \
        p0[r] = exp_raw(z0[r]);                                             \
        p1[r] = exp_raw(z1[r]);                                             \
      }                                                                     \
      union { unsigned u[4]; s16x8 v; } pb;                                 \
      pb.u[0] = cvtpk(p0[0], p0[1]);                                        \
      pb.u[1] = cvtpk(p0[2], p0[3]);                                        \
      pb.u[2] = cvtpk(p1[0], p1[1]);                                        \
      pb.u[3] = cvtpk(p1[2], p1[3]);                                        \
      oacc[ig][0] = MFMA16(VF##0, pb.v, oacc[ig][0]);                       \
      oacc[ig][1] = MFMA16(VF##1, pb.v, oacc[ig][1]);                       \
      oacc[ig][2] = MFMA16(VF##2, pb.v, oacc[ig][2]);                       \
      oacc[ig][3] = MFMA16(VF##3, pb.v, oacc[ig][3]);                       \
      lacc[ig] = MFMA16(ones, pb.v, lacc[ig]);                              \
    }                                                                       \
  } while (0)

__global__ __launch_bounds__(256, 2) void attn(const short* __restrict__ qT_,
                                               const short* __restrict__ kP,
                                               const short* __restrict__ vP,
                                               short* __restrict__ ao_) {
  __shared__ __align__(16) f32x4 cb[2 * 1088];  // 2 regions x 17 items x 64 lanes
  int bid = blockIdx.x;
  int bh = bid & 7, itile = bid >> 3;  // bh -> XCD (round-robin)
  int b = bh >> 2, h = bh & 3;
  int i0 = itile * 64;
  const short* kp = kP + (long)bh * 128 * 2048;
  const short* vp = vP + (long)bh * 128 * 2048;
  short* ao = ao_ + (long)b * 4096 * 256;
  int t = threadIdx.x, wv = t >> 6, l = t & 63, lq = l & 15, lg = l >> 4;

  s16x8 ones;
#pragma unroll
  for (int r = 0; r < 8; r++) ones[r] = (short)0x3F80;  // bf16 1.0

  // Q fragments, resident for the whole kernel
  s16x8 qf[4][2];
  const short* qbase = qT_ + (long)b * 4096 * 256 + h * 64;
#pragma unroll
  for (int ig = 0; ig < 4; ig++) {
    const short* qr = qbase + (long)(i0 + ig * 16 + lq) * 256;
    qf[ig][0] = *(const s16x8*)(qr + 8 * lg);
    qf[ig][1] = *(const s16x8*)(qr + 32 + 8 * lg);
  }

  f32x4 oacc[4][4] = {};
  f32x4 lacc[4] = {};

  s16x8 ka0, ka1, ka2, ka3, va0, va1, va2, va3;
  s16x8 kb0, kb1, kb2, kb3, vb0, vb1, vb2, vb3;

  LOADKV(ka, va, 0);
  for (int jt = 0; jt < 32; jt += 2) {
    LOADKV(kb, vb, jt + 1);
    COMPUTE(ka, va);
    if (jt + 2 < 32) LOADKV(ka, va, jt + 2);
    COMPUTE(kb, vb);
  }

  // ---- l: lacc[ig][0] already holds sum over the wave's 32-j strip ----
  f32x4 lv4 = {lacc[0][0], lacc[1][0], lacc[2][0], lacc[3][0]};

  // ---- 2-round cross-wave combine tree ----
#define CB_W(REG)                                                           \
  do {                                                                      \
    f32x4* d_ = cb + (REG) * 1088;                                          \
    _Pragma("unroll") for (int ig = 0; ig < 4; ig++)                        \
    _Pragma("unroll") for (int nc = 0; nc < 4; nc++)                        \
        d_[(ig * 4 + nc) * 64 + l] = oacc[ig][nc];                          \
    d_[16 * 64 + l] = lv4;                                                  \
  } while (0)
#define CB_A(REG)                                                           \
  do {                                                                      \
    f32x4* s_ = cb + (REG) * 1088;                                          \
    _Pragma("unroll") for (int ig = 0; ig < 4; ig++)                        \
    _Pragma("unroll") for (int nc = 0; nc < 4; nc++)                        \
        oacc[ig][nc] += s_[(ig * 4 + nc) * 64 + l];                         \
    lv4 += s_[16 * 64 + l];                                                 \
  } while (0)

  if (wv >= 2) CB_W(wv - 2);
  __syncthreads();
  if (wv < 2) CB_A(wv);
  __syncthreads();
  if (wv == 1) CB_W(0);
  __syncthreads();
  if (wv == 0) {
    CB_A(0);
#pragma unroll
    for (int ig = 0; ig < 4; ig++) {
      float inv = 1.0f / lv4[ig];
      long irow = i0 + ig * 16 + lq;
#pragma unroll
      for (int nc = 0; nc < 4; nc++) {
        f32x4 o = oacc[ig][nc];
        unsigned u0 = cvtpk(o[0] * inv, o[1] * inv);
        unsigned u1 = cvtpk(o[2] * inv, o[3] * inv);
        *(unsigned long long*)&ao[irow * 256 + h * 64 + nc * 16 + 4 * lg] =
            ((unsigned long long)u1 << 32) | u0;
      }
    }
  }
}

// ---------------- K5: proj TN-GEMM (M-tile 32) + bias + GN residual --------
__global__ __launch_bounds__(256) void proj_gemm(const short* __restrict__ ao,
                                                 const short* __restrict__ wpb,
                                                 const float* __restrict__ bproj,
                                                 const float* __restrict__ x,
                                                 const float* __restrict__ gamma,
                                                 const float* __restrict__ beta,
                                                 const float* __restrict__ part,
                                                 float* __restrict__ out) {
  __shared__ __align__(16) short As[32 * 32];
  __shared__ __align__(16) short Bs[128 * 32];
  __shared__ float sstats[32];
  int m0 = blockIdx.x * 32, n0 = blockIdx.y * 128, b = blockIdx.z;
  const short* A = ao + (long)b * 4096 * 256;
  int t = threadIdx.x, wv = t >> 6, lane = t & 63, lg = lane >> 4, lq = lane & 15;
  int wr = wv >> 1, wc = wv & 1;
  stats_prologue(part, sstats, t);
  f32x4 acc[4] = {};
  for (int kt = 0; kt < 8; kt++) {
    int k0 = kt * 32;
    if (t < 128) {
      int row = t >> 2, kch = t & 3;
      int kk = kch ^ ((row >> 1) & 3);
      gload16(A + (m0 + row) * 256 + k0 + kk * 8, &As[wv * 512]);
    }
#pragma unroll
    for (int it = 0; it < 2; it++) {
      int chunk = t + it * 256;
      int row = chunk >> 2, kch = chunk & 3;
      int kk = kch ^ ((row >> 1) & 3);
      gload16(wpb + (n0 + row) * 256 + k0 + kk * 8, &Bs[it * 2048 + wv * 512]);
    }
    __syncthreads();
    s16x8 af, bfr[4];
    {
      int row = wr * 16 + lq;
      af = *(const s16x8*)&As[row * 32 + ((lg ^ ((row >> 1) & 3)) << 3)];
    }
#pragma unroll
    for (int ni = 0; ni < 4; ni++) {
      int row = wc * 64 + ni * 16 + lq;
      bfr[ni] = *(const s16x8*)&Bs[row * 32 + ((lg ^ ((row >> 1) & 3)) << 3)];
    }
#pragma unroll
    for (int ni = 0; ni < 4; ni++) acc[ni] = MFMA16(af, bfr[ni], acc[ni]);
    __syncthreads();
  }
#pragma unroll
  for (int ni = 0; ni < 4; ni++) {
    int p = m0 + wr * 16 + (lg << 2);
    int o = n0 + wc * 64 + ni * 16 + lq;
    int g = b * 8 + (o >> 5);
    float mean = sstats[g * 2], rstd = sstats[g * 2 + 1];
    float ga = gamma[o] * rstd;
    float be = beta[o] - mean * ga + bproj[o];
    long idx = ((long)(b * 256 + o)) * 4096 + p;
    float4 xv = *(const float4*)(x + idx);
    float4 ov = {acc[ni][0] + xv.x * ga + be, acc[ni][1] + xv.y * ga + be,
                 acc[ni][2] + xv.z * ga + be, acc[ni][3] + xv.w * ga + be};
    *(float4*)(out + idx) = ov;
  }
}

// ---------------------------------------------------------------------------
extern "C" void kernel_launch(void* const* d_in, const int* in_sizes, int n_in,
                              void* d_out, int out_size, void* d_ws, size_t ws_size,
                              hipStream_t stream) {
  const float* x = (const float*)d_in[0];
  const float* gamma = (const float*)d_in[1];
  const float* beta = (const float*)d_in[2];
  const float* wq = (const float*)d_in[3];
  const float* wp = (const float*)d_in[4];
  const float* bp = (const float*)d_in[5];
  float* out = (float*)d_out;
  char* ws = (char*)d_ws;

  short* xnT = (short*)(ws + 0);                //  4 MB  bf16 (b,p,c)
  short* wqb = (short*)(ws + 4194304);          //  384KB
  short* wpb = (short*)(ws + 4587520);          //  128KB
  short* qT = (short*)(ws + 4718592);           //  4 MB  bf16 (b,p,256) Q
  short* kP = (short*)(ws + 8912896);           //  4 MB  bf16 fragged K
  short* vP = (short*)(ws + 13107200);          //  4 MB  bf16 fragged V
  short* ao = (short*)(ws + 17301504);          //  4 MB  bf16 (b,p,C)
  float* gpart = (float*)(ws + 21495808);       //  2 KB

  pre_gn<<<1280, 256, 0, stream>>>(x, wq, wp, wqb, wpb, gpart);
  gn_norm_t<<<512, 256, 0, stream>>>(x, gamma, beta, gpart, xnT);
  qkv_gemm<<<dim3(64, 6, 2), 256, 0, stream>>>(xnT, wqb, qT, kP, vP);
  attn<<<512, 256, 0, stream>>>(qT, kP, vP, ao);
  proj_gemm<<<dim3(128, 2, 2), 256, 0, stream>>>(ao, wpb, bp, x, gamma, beta, gpart, out);
}

// Round 15
// 65.111 us; speedup vs baseline: 1.6027x; 1.0313x over previous
//
#include <hip/hip_runtime.h>

// ---------------------------------------------------------------------------
// AttentionBlock: GN(8 groups) -> QKV(768x256) -> 4-head attn (HW=4096, d=64)
//                 -> proj(256x256)+bias -> +xn residual.   B=2, C=256.
// R15: qkv_gemm and proj_gemm move to BK=64 (half the barriers, 2x MFMA per
// staging phase, 8-chunk XOR swizzle row&7). attn frozen at R14 (40.2us:
// coalesced pre-fragmented K/V, lane-local fixed-shift softmax, ones-MFMA
// l-sum, 2-deep ping-pong -- all scaling levers measured-closed).
// ---------------------------------------------------------------------------

typedef short s16x8 __attribute__((ext_vector_type(8)));
typedef float f32x4 __attribute__((ext_vector_type(4)));

#define MFMA16(a, b, c) __builtin_amdgcn_mfma_f32_16x16x32_bf16(a, b, c, 0, 0, 0)

__device__ __forceinline__ short bf16s(float f) {
  union { float f; unsigned u; } v; v.f = f;
  unsigned r = v.u + 0x7fffu + ((v.u >> 16) & 1u);
  return (short)(r >> 16);
}

__device__ __forceinline__ unsigned cvtpk(float lo, float hi) {
  unsigned r;
  asm("v_cvt_pk_bf16_f32 %0, %1, %2" : "=v"(r) : "v"(lo), "v"(hi));
  return r;
}

// 2^x via single v_exp_f32 (hazard-safe builtin). |x| < ~30 in this kernel.
__device__ __forceinline__ float exp_raw(float x) {
  return __builtin_amdgcn_exp2f(x);
}

__device__ __forceinline__ void gload16(const void* g, void* l) {
  __builtin_amdgcn_global_load_lds(
      (const __attribute__((address_space(1))) unsigned*)g,
      (__attribute__((address_space(3))) unsigned*)l, 16, 0, 0);
}

// ---------------- K1: GN partial sums (blk<256) + weight->bf16 (blk>=256) ---
__global__ __launch_bounds__(256) void pre_gn(const float* __restrict__ x,
                                              const float* __restrict__ wq,
                                              const float* __restrict__ wp,
                                              short* __restrict__ wqb,
                                              short* __restrict__ wpb,
                                              float* __restrict__ part) {
  int blk = blockIdx.x;
  int t = threadIdx.x;
  if (blk >= 256) {  // ---- weights -> bf16 ----
    int i = (blk - 256) * 256 + t;
    if (i < 768 * 256) {
      wqb[i] = bf16s(wq[i]);
    } else {
      int j = i - 768 * 256;
      if (j < 256 * 256) wpb[j] = bf16s(wp[j]);
    }
    return;
  }
  // ---- GN partial sums (16 groups x 16 parts) ----
  int gi = blk >> 4, sub = blk & 15;
  const float* base = x + (long)gi * 131072 + sub * 8192;
  float s = 0.f, ss = 0.f;
#pragma unroll
  for (int k = 0; k < 8; k++) {
    float4 v = *(const float4*)(base + t * 4 + k * 1024);
    s += v.x + v.y + v.z + v.w;
    ss += v.x * v.x + v.y * v.y + v.z * v.z + v.w * v.w;
  }
#pragma unroll
  for (int m = 1; m < 64; m <<= 1) { s += __shfl_xor(s, m); ss += __shfl_xor(ss, m); }
  __shared__ float red[8];
  int wv = t >> 6;
  if ((t & 63) == 0) { red[wv * 2] = s; red[wv * 2 + 1] = ss; }
  __syncthreads();
  if (t == 0) {
    float S = 0.f, SS = 0.f;
    for (int w = 0; w < 4; w++) { S += red[w * 2]; SS += red[w * 2 + 1]; }
    part[blk * 2] = S; part[blk * 2 + 1] = SS;
  }
}

// stats-from-partials prologue (16 groups; g = b*8 + c/32)
__device__ __forceinline__ void stats_prologue(const float* __restrict__ part,
                                               float* sstats, int t) {
  if (t < 16) {
    float S = 0.f, SS = 0.f;
#pragma unroll
    for (int i = 0; i < 16; i++) {
      S += part[(t * 16 + i) * 2];
      SS += part[(t * 16 + i) * 2 + 1];
    }
    float mean = S * (1.0f / 131072.0f);
    float var = SS * (1.0f / 131072.0f) - mean * mean;
    sstats[t * 2] = mean;
    sstats[t * 2 + 1] = rsqrtf(var + 1e-5f);
  }
}

// ---------------- K2: normalize + transpose -> xnT bf16 (p,c) --------------
__global__ __launch_bounds__(256) void gn_norm_t(const float* __restrict__ x,
                                                 const float* __restrict__ gamma,
                                                 const float* __restrict__ beta,
                                                 const float* __restrict__ part,
                                                 short* __restrict__ xnT) {
  __shared__ __align__(16) short T[64 * 88];
  __shared__ float sstats[32];
  int bx = blockIdx.x;
  int pt = bx & 63, ct = (bx >> 6) & 3, b = bx >> 8;
  int t = threadIdx.x;
  stats_prologue(part, sstats, t);
  __syncthreads();
#pragma unroll
  for (int it = 0; it < 4; it++) {
    int chunk = t + it * 256;
    int c_loc = chunk >> 4, pch = chunk & 15;
    int c = ct * 64 + c_loc;
    int g = b * 8 + (c >> 5);
    float mean = sstats[g * 2], rstd = sstats[g * 2 + 1];
    float ga = gamma[c] * rstd;
    float be = beta[c] - mean * ga;
    long idx = ((long)(b * 256 + c)) * 4096 + pt * 64 + pch * 4;
    float4 v = *(const float4*)(x + idx);
    float4 n = {v.x * ga + be, v.y * ga + be, v.z * ga + be, v.w * ga + be};
    int p0 = pch * 4;
    T[(p0 + 0) * 88 + c_loc] = bf16s(n.x);
    T[(p0 + 1) * 88 + c_loc] = bf16s(n.y);
    T[(p0 + 2) * 88 + c_loc] = bf16s(n.z);
    T[(p0 + 3) * 88 + c_loc] = bf16s(n.w);
  }
  __syncthreads();
#pragma unroll
  for (int it = 0; it < 2; it++) {
    int chunk = t + it * 256;
    int p_loc = chunk >> 3, cch = chunk & 7;
    s16x8 v = *(const s16x8*)&T[p_loc * 88 + cch * 8];
    *(s16x8*)&xnT[((long)(b * 4096 + pt * 64 + p_loc)) * 256 + ct * 64 + cch * 8] = v;
  }
}

// ---------------- K3: QKV TN-GEMM, M-tile 64, BK=64 -------------------------
// D[p,o] = xnT[p,:] . wq[o,:].
//   y<2: Q (scaled 0.125*log2 e) -> qT via LDS transpose, coalesced stores
//   y in {2,3}: K -> kP via LDS transpose, coalesced 16B stores
//   y in {4,5}: V -> vP (u64 stores)
__global__ __launch_bounds__(256) void qkv_gemm(const short* __restrict__ xnT,
                                                const short* __restrict__ wqb,
                                                short* __restrict__ qT,
                                                short* __restrict__ kP,
                                                short* __restrict__ vP) {
  __shared__ __align__(16) short smem[12288];  // As 64x64 | Bs 128x64 ; Ts 64x130
  short* As = smem;
  short* Bs = smem + 4096;
  int m0 = blockIdx.x * 64, n0 = blockIdx.y * 128, b = blockIdx.z;
  const short* A = xnT + (long)b * 4096 * 256;
  int t = threadIdx.x, wv = t >> 6, lane = t & 63, lg = lane >> 4, lq = lane & 15;
  int wr = wv >> 1, wc = wv & 1;
  f32x4 acc[2][4] = {};
  for (int kt = 0; kt < 4; kt++) {
    int k0 = kt * 64;
#pragma unroll
    for (int it = 0; it < 2; it++) {
      int chunk = t + it * 256;
      int row = chunk >> 3, kch = chunk & 7;
      int kk = kch ^ (row & 7);
      gload16(A + (m0 + row) * 256 + k0 + kk * 8, &As[it * 2048 + wv * 512]);
    }
#pragma unroll
    for (int it = 0; it < 4; it++) {
      int chunk = t + it * 256;
      int row = chunk >> 3, kch = chunk & 7;
      int kk = kch ^ (row & 7);
      gload16(wqb + (n0 + row) * 256 + k0 + kk * 8, &Bs[it * 2048 + wv * 512]);
    }
    __syncthreads();
    s16x8 af[2][2], bfr[4][2];
#pragma unroll
    for (int mi = 0; mi < 2; mi++) {
      int row = wr * 32 + mi * 16 + lq;
#pragma unroll
      for (int h = 0; h < 2; h++)
        af[mi][h] = *(const s16x8*)&As[row * 64 + (((h * 4 + lg) ^ (row & 7)) << 3)];
    }
#pragma unroll
    for (int ni = 0; ni < 4; ni++) {
      int row = wc * 64 + ni * 16 + lq;
#pragma unroll
      for (int h = 0; h < 2; h++)
        bfr[ni][h] = *(const s16x8*)&Bs[row * 64 + (((h * 4 + lg) ^ (row & 7)) << 3)];
    }
#pragma unroll
    for (int mi = 0; mi < 2; mi++)
#pragma unroll
      for (int ni = 0; ni < 4; ni++) {
        acc[mi][ni] = MFMA16(af[mi][0], bfr[ni][0], acc[mi][ni]);
        acc[mi][ni] = MFMA16(af[mi][1], bfr[ni][1], acc[mi][ni]);
      }
    __syncthreads();
  }
  if (blockIdx.y < 2) {  // ---- Q: LDS transpose -> coalesced qT stores ----
    short(*Ts)[130] = (short(*)[130])smem;
#pragma unroll
    for (int mi = 0; mi < 2; mi++)
#pragma unroll
      for (int ni = 0; ni < 4; ni++) {
        int pr = wr * 32 + mi * 16 + (lg << 2);
        int oc = wc * 64 + ni * 16 + lq;
#pragma unroll
        for (int r = 0; r < 4; r++)
          Ts[pr + r][oc] = bf16s(acc[mi][ni][r] * 0.180336880f);
      }
    __syncthreads();
    short* Out = qT + (long)b * 4096 * 256;
#pragma unroll
    for (int it = 0; it < 4; it++) {
      int chunk = t + it * 256;
      int row = chunk >> 4, cc8 = (chunk & 15) * 8;
      s16x8 v = *(const s16x8*)&Ts[row][cc8];
      *(s16x8*)&Out[(long)(m0 + row) * 256 + n0 + cc8] = v;
    }
  } else if (blockIdx.y < 4) {  // ---- K: LDS transpose -> coalesced kP ----
    short(*Ts)[130] = (short(*)[130])smem;
#pragma unroll
    for (int mi = 0; mi < 2; mi++)
#pragma unroll
      for (int ni = 0; ni < 4; ni++) {
        int pr = wr * 32 + mi * 16 + (lg << 2);
        int oc = wc * 64 + ni * 16 + lq;
#pragma unroll
        for (int r = 0; r < 4; r++) Ts[pr + r][oc] = bf16s(acc[mi][ni][r]);
      }
    __syncthreads();
    int reg = t >> 6;
    int tl = reg >> 1, hl = reg & 1;
    int l2 = t & 63, lq2 = l2 & 15, lg2 = l2 >> 4;
    int hb = (n0 - 256) >> 6;
    long kb2 = ((long)(b * 4 + hb + hl) * 128 + (m0 >> 5) + tl) * 2048;
#pragma unroll
    for (int f = 0; f < 4; f++) {
      int row = 32 * tl + (lq2 & 3) + 8 * (lq2 >> 2) + 4 * (f >> 1);  // pi(lq2)
      int col = hl * 64 + 32 * (f & 1) + 8 * lg2;
      s16x8 v = *(const s16x8*)&Ts[row][col];
      *(s16x8*)&kP[kb2 + f * 512 + l2 * 8] = v;
    }
  } else {  // ---- V -> vP ----
#pragma unroll
    for (int mi = 0; mi < 2; mi++)
#pragma unroll
      for (int ni = 0; ni < 4; ni++) {
        int p = m0 + wr * 32 + mi * 16 + (lg << 2);
        int c = (n0 - 512) + wc * 64 + ni * 16 + lq;
        int h = c >> 6, ch = c & 63;
        int f = ch >> 4, lqp = ch & 15;
        int tile = p >> 5, lgp = (p & 31) >> 3, e0 = p & 7;
        unsigned u0 = cvtpk(acc[mi][ni][0], acc[mi][ni][1]);
        unsigned u1 = cvtpk(acc[mi][ni][2], acc[mi][ni][3]);
        *(unsigned long long*)&vP[((long)(b * 4 + h) * 128 + tile) * 2048 +
                                  f * 512 + (lgp * 16 + lqp) * 8 + e0] =
            ((unsigned long long)u1 << 32) | u0;
      }
  }
}

// ---------------- K4: flash attention (R14-exact, frozen) -------------------
#define LOADKV(KF, VF, JT)                                                  \
  do {                                                                      \
    long tb_ = ((long)((JT) * 4 + wv)) * 2048 + l * 8;                      \
    KF##0 = *(const s16x8*)(kp + tb_);                                      \
    KF##1 = *(const s16x8*)(kp + tb_ + 512);                                \
    KF##2 = *(const s16x8*)(kp + tb_ + 1024);                               \
    KF##3 = *(const s16x8*)(kp + tb_ + 1536);                               \
    VF##0 = *(const s16x8*)(vp + tb_);                                      \
    VF##1 = *(const s16x8*)(vp + tb_ + 512);                                \
    VF##2 = *(const s16x8*)(vp + tb_ + 1024);                               \
    VF##3 = *(const s16x8*)(vp + tb_ + 1536);                               \
  } while (0)

#define COMPUTE(KF, VF)                                                     \
  do {                                                                      \
    _Pragma("unroll") for (int ig = 0; ig < 4; ig++) {                      \
      f32x4 z0 = {0.f, 0.f, 0.f, 0.f}, z1 = {0.f, 0.f, 0.f, 0.f};           \
      z0 = MFMA16(KF##0, qf[ig][0], z0);                                    \
      z0 = MFMA16(KF##1, qf[ig][1], z0);                                    \
      z1 = MFMA16(KF##2, qf[ig][0], z1);                                    \
      z1 = MFMA16(KF##3, qf[ig][1], z1);                                    \
      f32x4 p0, p1;                                                         \
      _Pragma("unroll") for (int r = 0; r < 4; r++) {                       \
        p0[r] = exp_raw(z0[r]);                                             \
        p1[r] = exp_raw(z1[r]);                                             \
      }                                                                     \
      union { unsigned u[4]; s16x8 v; } pb;                                 \
      pb.u[0] = cvtpk(p0[0], p0[1]);                                        \
      pb.u[1] = cvtpk(p0[2], p0[3]);                                        \
      pb.u[2] = cvtpk(p1[0], p1[1]);                                        \
      pb.u[3] = cvtpk(p1[2], p1[3]);                                        \
      oacc[ig][0] = MFMA16(VF##0, pb.v, oacc[ig][0]);                       \
      oacc[ig][1] = MFMA16(VF##1, pb.v, oacc[ig][1]);                       \
      oacc[ig][2] = MFMA16(VF##2, pb.v, oacc[ig][2]);                       \
      oacc[ig][3] = MFMA16(VF##3, pb.v, oacc[ig][3]);                       \
      lacc[ig] = MFMA16(ones, pb.v, lacc[ig]);                              \
    }                                                                       \
  } while (0)

__global__ __launch_bounds__(256, 2) void attn(const short* __restrict__ qT_,
                                               const short* __restrict__ kP,
                                               const short* __restrict__ vP,
                                               short* __restrict__ ao_) {
  __shared__ __align__(16) f32x4 cb[2 * 1088];  // 2 regions x 17 items x 64 lanes
  int bid = blockIdx.x;
  int bh = bid & 7, itile = bid >> 3;  // bh -> XCD (round-robin)
  int b = bh >> 2, h = bh & 3;
  int i0 = itile * 64;
  const short* kp = kP + (long)bh * 128 * 2048;
  const short* vp = vP + (long)bh * 128 * 2048;
  short* ao = ao_ + (long)b * 4096 * 256;
  int t = threadIdx.x, wv = t >> 6, l = t & 63, lq = l & 15, lg = l >> 4;

  s16x8 ones;
#pragma unroll
  for (int r = 0; r < 8; r++) ones[r] = (short)0x3F80;  // bf16 1.0

  // Q fragments, resident for the whole kernel
  s16x8 qf[4][2];
  const short* qbase = qT_ + (long)b * 4096 * 256 + h * 64;
#pragma unroll
  for (int ig = 0; ig < 4; ig++) {
    const short* qr = qbase + (long)(i0 + ig * 16 + lq) * 256;
    qf[ig][0] = *(const s16x8*)(qr + 8 * lg);
    qf[ig][1] = *(const s16x8*)(qr + 32 + 8 * lg);
  }

  f32x4 oacc[4][4] = {};
  f32x4 lacc[4] = {};

  s16x8 ka0, ka1, ka2, ka3, va0, va1, va2, va3;
  s16x8 kb0, kb1, kb2, kb3, vb0, vb1, vb2, vb3;

  LOADKV(ka, va, 0);
  for (int jt = 0; jt < 32; jt += 2) {
    LOADKV(kb, vb, jt + 1);
    COMPUTE(ka, va);
    if (jt + 2 < 32) LOADKV(ka, va, jt + 2);
    COMPUTE(kb, vb);
  }

  // ---- l: lacc[ig][0] already holds sum over the wave's 32-j strip ----
  f32x4 lv4 = {lacc[0][0], lacc[1][0], lacc[2][0], lacc[3][0]};

  // ---- 2-round cross-wave combine tree ----
#define CB_W(REG)                                                           \
  do {                                                                      \
    f32x4* d_ = cb + (REG) * 1088;                                          \
    _Pragma("unroll") for (int ig = 0; ig < 4; ig++)                        \
    _Pragma("unroll") for (int nc = 0; nc < 4; nc++)                        \
        d_[(ig * 4 + nc) * 64 + l] = oacc[ig][nc];                          \
    d_[16 * 64 + l] = lv4;                                                  \
  } while (0)
#define CB_A(REG)                                                           \
  do {                                                                      \
    f32x4* s_ = cb + (REG) * 1088;                                          \
    _Pragma("unroll") for (int ig = 0; ig < 4; ig++)                        \
    _Pragma("unroll") for (int nc = 0; nc < 4; nc++)                        \
        oacc[ig][nc] += s_[(ig * 4 + nc) * 64 + l];                         \
    lv4 += s_[16 * 64 + l];                                                 \
  } while (0)

  if (wv >= 2) CB_W(wv - 2);
  __syncthreads();
  if (wv < 2) CB_A(wv);
  __syncthreads();
  if (wv == 1) CB_W(0);
  __syncthreads();
  if (wv == 0) {
    CB_A(0);
#pragma unroll
    for (int ig = 0; ig < 4; ig++) {
      float inv = 1.0f / lv4[ig];
      long irow = i0 + ig * 16 + lq;
#pragma unroll
      for (int nc = 0; nc < 4; nc++) {
        f32x4 o = oacc[ig][nc];
        unsigned u0 = cvtpk(o[0] * inv, o[1] * inv);
        unsigned u1 = cvtpk(o[2] * inv, o[3] * inv);
        *(unsigned long long*)&ao[irow * 256 + h * 64 + nc * 16 + 4 * lg] =
            ((unsigned long long)u1 << 32) | u0;
      }
    }
  }
}

// ---------------- K5: proj TN-GEMM (M-tile 32, BK=64) + bias + residual ----
__global__ __launch_bounds__(256) void proj_gemm(const short* __restrict__ ao,
                                                 const short* __restrict__ wpb,
                                                 const float* __restrict__ bproj,
                                                 const float* __restrict__ x,
                                                 const float* __restrict__ gamma,
                                                 const float* __restrict__ beta,
                                                 const float* __restrict__ part,
                                                 float* __restrict__ out) {
  __shared__ __align__(16) short As[32 * 64];
  __shared__ __align__(16) short Bs[128 * 64];
  __shared__ float sstats[32];
  int m0 = blockIdx.x * 32, n0 = blockIdx.y * 128, b = blockIdx.z;
  const short* A = ao + (long)b * 4096 * 256;
  int t = threadIdx.x, wv = t >> 6, lane = t & 63, lg = lane >> 4, lq = lane & 15;
  int wr = wv >> 1, wc = wv & 1;
  stats_prologue(part, sstats, t);
  f32x4 acc[4] = {};
  for (int kt = 0; kt < 4; kt++) {
    int k0 = kt * 64;
    {
      int row = t >> 3, kch = t & 7;
      int kk = kch ^ (row & 7);
      gload16(A + (m0 + row) * 256 + k0 + kk * 8, &As[wv * 512]);
    }
#pragma unroll
    for (int it = 0; it < 4; it++) {
      int chunk = t + it * 256;
      int row = chunk >> 3, kch = chunk & 7;
      int kk = kch ^ (row & 7);
      gload16(wpb + (n0 + row) * 256 + k0 + kk * 8, &Bs[it * 2048 + wv * 512]);
    }
    __syncthreads();
    s16x8 af[2], bfr[4][2];
    {
      int row = wr * 16 + lq;
#pragma unroll
      for (int h = 0; h < 2; h++)
        af[h] = *(const s16x8*)&As[row * 64 + (((h * 4 + lg) ^ (row & 7)) << 3)];
    }
#pragma unroll
    for (int ni = 0; ni < 4; ni++) {
      int row = wc * 64 + ni * 16 + lq;
#pragma unroll
      for (int h = 0; h < 2; h++)
        bfr[ni][h] = *(const s16x8*)&Bs[row * 64 + (((h * 4 + lg) ^ (row & 7)) << 3)];
    }
#pragma unroll
    for (int ni = 0; ni < 4; ni++) {
      acc[ni] = MFMA16(af[0], bfr[ni][0], acc[ni]);
      acc[ni] = MFMA16(af[1], bfr[ni][1], acc[ni]);
    }
    __syncthreads();
  }
#pragma unroll
  for (int ni = 0; ni < 4; ni++) {
    int p = m0 + wr * 16 + (lg << 2);
    int o = n0 + wc * 64 + ni * 16 + lq;
    int g = b * 8 + (o >> 5);
    float mean = sstats[g * 2], rstd = sstats[g * 2 + 1];
    float ga = gamma[o] * rstd;
    float be = beta[o] - mean * ga + bproj[o];
    long idx = ((long)(b * 256 + o)) * 4096 + p;
    float4 xv = *(const float4*)(x + idx);
    float4 ov = {acc[ni][0] + xv.x * ga + be, acc[ni][1] + xv.y * ga + be,
                 acc[ni][2] + xv.z * ga + be, acc[ni][3] + xv.w * ga + be};
    *(float4*)(out + idx) = ov;
  }
}

// ---------------------------------------------------------------------------
extern "C" void kernel_launch(void* const* d_in, const int* in_sizes, int n_in,
                              void* d_out, int out_size, void* d_ws, size_t ws_size,
                              hipStream_t stream) {
  const float* x = (const float*)d_in[0];
  const float* gamma = (const float*)d_in[1];
  const float* beta = (const float*)d_in[2];
  const float* wq = (const float*)d_in[3];
  const float* wp = (const float*)d_in[4];
  const float* bp = (const float*)d_in[5];
  float* out = (float*)d_out;
  char* ws = (char*)d_ws;

  short* xnT = (short*)(ws + 0);                //  4 MB  bf16 (b,p,c)
  short* wqb = (short*)(ws + 4194304);          //  384KB
  short* wpb = (short*)(ws + 4587520);          //  128KB
  short* qT = (short*)(ws + 4718592);           //  4 MB  bf16 (b,p,256) Q
  short* kP = (short*)(ws + 8912896);           //  4 MB  bf16 fragged K
  short* vP = (short*)(ws + 13107200);          //  4 MB  bf16 fragged V
  short* ao = (short*)(ws + 17301504);          //  4 MB  bf16 (b,p,C)
  float* gpart = (float*)(ws + 21495808);       //  2 KB

  pre_gn<<<1280, 256, 0, stream>>>(x, wq, wp, wqb, wpb, gpart);
  gn_norm_t<<<512, 256, 0, stream>>>(x, gamma, beta, gpart, xnT);
  qkv_gemm<<<dim3(64, 6, 2), 256, 0, stream>>>(xnT, wqb, qT, kP, vP);
  attn<<<512, 256, 0, stream>>>(qT, kP, vP, ao);
  proj_gemm<<<dim3(128, 2, 2), 256, 0, stream>>>(ao, wpb, bp, x, gamma, beta, gpart, out);
}